// Round 3
// baseline (574.723 us; speedup 1.0000x reference)
//
#include <hip/hip_runtime.h>

typedef __attribute__((ext_vector_type(8))) short short8;
typedef __attribute__((ext_vector_type(8))) __bf16 bf16x8;
typedef __attribute__((ext_vector_type(4))) float f32x4;

// sizes
#define B_ 4
#define C_ 64
#define H_ 128
#define W_ 128
#define P_ (H_*W_)      // 16384
#define E_ 16
#define Kk 3

// ws layout (bytes)
#define OFF_XT   0u
#define XT_BYTES (4u*130u*130u*64u*2u)          // 8,652,800
#define OFF_A    8652800u
#define A_BYTES  (1024u*576u*2u)                 // 1,179,648
#define OFF_R1   9832448u
#define R1_BYTES (4u*16u*16384u*4u)              // 4,194,304
#define OFF_PARA 14026752u

__device__ inline unsigned short f2bf(float f) {
    union { float f; unsigned u; } v; v.f = f;
    unsigned r = v.u + 0x7FFF + ((v.u >> 16) & 1);
    return (unsigned short)(r >> 16);
}

// ---------- zero xt (borders must be 0; simpler to zero all) ----------
__global__ __launch_bounds__(256) void k_zero(unsigned short* __restrict__ xt) {
    int i = blockIdx.x * 256 + threadIdx.x;
    if (i < (int)(XT_BYTES / 16)) {
        short8 z = {0,0,0,0,0,0,0,0};
        ((short8*)xt)[i] = z;
    }
}

// ---------- transpose+pad x (NCHW f32) -> xt[b][y+1][x+1][c] bf16 ----------
__global__ __launch_bounds__(128) void k_transpose(const float* __restrict__ x,
                                                   unsigned short* __restrict__ xt) {
    int b = blockIdx.x >> 7, y = blockIdx.x & 127;
    int t = threadIdx.x; // x coordinate
    const float* src = x + (size_t)b * C_ * P_ + y * W_ + t;
    unsigned short* dst = xt + ((size_t)(b * 130 + y + 1) * 130 + t + 1) * 64;
#pragma unroll
    for (int i = 0; i < 8; ++i) {
        short8 v;
#pragma unroll
        for (int j = 0; j < 8; ++j) v[j] = (short)f2bf(src[(size_t)(i * 8 + j) * P_]);
        ((short8*)dst)[i] = v;
    }
}

// ---------- build A[row=o*16+e][col=(kh*3+kw)*64+c] bf16 from W ----------
__global__ __launch_bounds__(256) void k_prepA(const float* __restrict__ Wsrc,
                                               unsigned short* __restrict__ A) {
    __shared__ float lw[9216];
    int o = blockIdx.x, t = threadIdx.x;
    const float* src = Wsrc + (size_t)o * 9216; // 576*16 per o, layout [j=c*9+tap][e]
    for (int lin = t; lin < 9216; lin += 256) lw[lin] = src[lin];
    __syncthreads();
    unsigned short* dst = A + (size_t)o * 16 * 576;
    for (int lin = t; lin < 9216; lin += 256) {
        int e = lin / 576, col = lin - e * 576;
        int tap = col >> 6, c = col & 63;
        dst[e * 576 + col] = f2bf(lw[(c * 9 + tap) * 16 + e]);
    }
}

// ---------- predictor conv1x1 + relu -> r1[b][e][p] f32 ----------
__global__ __launch_bounds__(256) void k_pred1(const float* __restrict__ x,
                                               const float* __restrict__ pw,
                                               const float* __restrict__ pb,
                                               float* __restrict__ r1) {
    __shared__ float lpw[1024];
    __shared__ float lpb[16];
    int t = threadIdx.x;
    for (int lin = t; lin < 1024; lin += 256) lpw[lin] = pw[lin];
    if (t < 16) lpb[t] = pb[t];
    __syncthreads();
    int gp = blockIdx.x * 256 + t;
    int b = gp >> 14, p = gp & 16383;
    const float* xs = x + (size_t)b * C_ * P_ + p;
    float s[16];
#pragma unroll
    for (int e = 0; e < 16; ++e) s[e] = lpb[e];
    for (int c = 0; c < 64; ++c) {
        float xv = xs[(size_t)c * P_];
#pragma unroll
        for (int e = 0; e < 16; ++e) s[e] = fmaf(lpw[e * 64 + c], xv, s[e]);
    }
    float* d = r1 + (size_t)b * 16 * P_ + p;
#pragma unroll
    for (int e = 0; e < 16; ++e) d[(size_t)e * P_] = fmaxf(s[e], 0.f);
}

// ---------- predictor conv3x3 -> para[b][e][p] f32 ----------
__global__ __launch_bounds__(256) void k_pred2(const float* __restrict__ r1,
                                               const float* __restrict__ cw,
                                               const float* __restrict__ cb,
                                               float* __restrict__ para) {
    __shared__ float lcw[2304];
    __shared__ float lcb[16];
    int t = threadIdx.x;
    for (int lin = t; lin < 2304; lin += 256) lcw[lin] = cw[lin];
    if (t < 16) lcb[t] = cb[t];
    __syncthreads();
    int gp = blockIdx.x * 256 + t;
    int b = gp >> 14, p = gp & 16383;
    int y = p >> 7, xc = p & 127;
    const float* rs = r1 + (size_t)b * 16 * P_;
    float s[16];
#pragma unroll
    for (int e = 0; e < 16; ++e) s[e] = lcb[e];
    for (int dy = 0; dy < 3; ++dy) {
        int yy = y + dy - 1;
        if (yy < 0 || yy > 127) continue;
        for (int dx = 0; dx < 3; ++dx) {
            int xv = xc + dx - 1;
            if (xv < 0 || xv > 127) continue;
            int q = yy * 128 + xv;
            int tap = dy * 3 + dx;
#pragma unroll
            for (int ep = 0; ep < 16; ++ep) {
                float v = rs[(size_t)ep * P_ + q];
#pragma unroll
                for (int e = 0; e < 16; ++e)
                    s[e] = fmaf(lcw[(e * 16 + ep) * 9 + tap], v, s[e]);
            }
        }
    }
    float* d = para + (size_t)b * 16 * P_ + p;
#pragma unroll
    for (int e = 0; e < 16; ++e) d[(size_t)e * P_] = s[e];
}

// ---------- main fused kernel ----------
// block = 512 threads (8 waves): 4 image rows x 16 output channels (osl).
// wave: wrow = wave&3 (image row), ohalf = wave>>2 (8 o's via 4 chunks x 2 f).
// ks-loop fully unrolled, double-buffered prefetch (A from L2, B from LDS),
// zero per-ks address VALU (precomputed vaddrs + immediate offsets).
__global__ __launch_bounds__(512, 2) void k_main(const unsigned short* __restrict__ xt,
                                                 const unsigned short* __restrict__ A,
                                                 const float* __restrict__ para,
                                                 float* __restrict__ out) {
    __shared__ unsigned short lds[6 * 130 * 64]; // 99,840 B
    int r = blockIdx.x;
    int xcd = r & 7;
    int ord = r >> 3;
    int osl = ord & 3;          // o-slice: 16 o's
    int bygl = ord >> 2;        // [0,16)
    int byg = bygl * 8 + xcd;   // [0,128)
    int b = byg >> 5, yg = byg & 31;
    int y0 = yg * 4;            // first image row of this block

    int tid = threadIdx.x;
    int wave = tid >> 6, lane = tid & 63, lhi = lane >> 4, llo = lane & 15;
    int wrow = wave & 3, ohalf = wave >> 2;

    // stage 6 padded xt rows (y0 .. y0+5), swizzle byte ^= ((xx&7)<<4)
    const unsigned short* xrow = xt + (size_t)(b * 130 + y0) * 130 * 64;
    for (int ci = tid; ci < 6240; ci += 512) {
        int row = ci / 1040, rem = ci - row * 1040;
        int xx = rem >> 3, cc = rem & 7;
        short8 v = *(const short8*)(xrow + ((size_t)row * 130 + xx) * 64 + cc * 8);
        int lb = row * 16640 + xx * 128 + ((cc * 16) ^ ((xx & 7) << 4));
        *(short8*)((char*)lds + lb) = v;
    }
    __syncthreads();

    int y = y0 + wrow;
    const float* pp = para + (size_t)b * 16 * P_ + y * 128;
    float* po = out + (size_t)b * 64 * P_ + y * 128;

    // precomputed LDS read vaddrs: qv[parity][kw]; full addr = qv + kh*16640 + pg*2048
    int qv[2][3];
#pragma unroll
    for (int kw = 0; kw < 3; ++kw) {
        int rowi = llo + kw;
        int base0 = wrow * 16640 + rowi * 128 + ((lhi * 16) ^ ((rowi & 7) << 4));
        qv[0][kw] = base0;
        qv[1][kw] = base0 ^ 64;
    }
    const char* ldsc = (const char*)lds;

    // para values for the epilogue reduction (chunk-invariant)
    float pvv[8][4];
#pragma unroll
    for (int pg = 0; pg < 8; ++pg)
#pragma unroll
        for (int rr = 0; rr < 4; ++rr)
            pvv[pg][rr] = pp[(size_t)(lhi * 4 + rr) * P_ + pg * 16 + llo];

#define LOAD_AF(dst, ksv) do { \
        dst[0] = *(const bf16x8*)(Ap0 + (ksv) * 32); \
        dst[1] = *(const bf16x8*)(Ap1 + (ksv) * 32); \
    } while (0)

#define LOAD_BF(dst, ksv) do { \
        const int kh_ = (ksv) / 6, kw_ = ((ksv) - kh_ * 6) >> 1, par_ = (ksv) & 1; \
        const char* bp_ = ldsc + qv[par_][kw_] + kh_ * 16640; \
        _Pragma("unroll") \
        for (int pg_ = 0; pg_ < 8; ++pg_) dst[pg_] = *(const bf16x8*)(bp_ + pg_ * 2048); \
    } while (0)

#define DO_MFMA(afb, bfb) do { \
        _Pragma("unroll") \
        for (int f_ = 0; f_ < 2; ++f_) \
        _Pragma("unroll") \
        for (int pg_ = 0; pg_ < 8; ++pg_) \
            acc[f_][pg_] = __builtin_amdgcn_mfma_f32_16x16x32_bf16(afb[f_], bfb[pg_], acc[f_][pg_], 0, 0, 0); \
    } while (0)

    for (int chunk = 0; chunk < 4; ++chunk) {
        int obase = osl * 16 + ohalf * 8 + chunk * 2;
        const unsigned short* Ap0 = A + (size_t)(obase * 16 + llo) * 576 + lhi * 8;
        const unsigned short* Ap1 = Ap0 + 9216;

        f32x4 acc[2][8];
#pragma unroll
        for (int f = 0; f < 2; ++f)
#pragma unroll
            for (int pg = 0; pg < 8; ++pg) acc[f][pg] = (f32x4){0.f, 0.f, 0.f, 0.f};

        bf16x8 afA[2], afB[2], bfA[8], bfB[8];
        LOAD_AF(afA, 0);
        LOAD_BF(bfA, 0);

#pragma unroll
        for (int ks = 0; ks < 18; ++ks) {
            if ((ks & 1) == 0) {
                if (ks < 17) { LOAD_AF(afB, ks + 1); LOAD_BF(bfB, ks + 1); }
                DO_MFMA(afA, bfA);
            } else {
                if (ks < 17) { LOAD_AF(afA, ks + 1); LOAD_BF(bfA, ks + 1); }
                DO_MFMA(afB, bfB);
            }
        }

        // epilogue: multiply rows (e) by para[e,p], reduce over e
#pragma unroll
        for (int f = 0; f < 2; ++f) {
            int o = obase + f;
#pragma unroll
            for (int pg = 0; pg < 8; ++pg) {
                float s = acc[f][pg][0] * pvv[pg][0] + acc[f][pg][1] * pvv[pg][1] +
                          acc[f][pg][2] * pvv[pg][2] + acc[f][pg][3] * pvv[pg][3];
                s += __shfl_xor(s, 16);
                s += __shfl_xor(s, 32);
                if (lhi == 0)
                    __builtin_nontemporal_store(s, &po[(size_t)o * P_ + pg * 16 + llo]);
            }
        }
    }
#undef LOAD_AF
#undef LOAD_BF
#undef DO_MFMA
}

extern "C" void kernel_launch(void* const* d_in, const int* in_sizes, int n_in,
                              void* d_out, int out_size, void* d_ws, size_t ws_size,
                              hipStream_t stream) {
    const float* x  = (const float*)d_in[0];
    const float* W  = (const float*)d_in[1];
    const float* pw = (const float*)d_in[2];
    const float* pb = (const float*)d_in[3];
    const float* cw = (const float*)d_in[4];
    const float* cb = (const float*)d_in[5];
    float* out = (float*)d_out;
    char* ws = (char*)d_ws;
    unsigned short* xt = (unsigned short*)(ws + OFF_XT);
    unsigned short* Am = (unsigned short*)(ws + OFF_A);
    float* r1   = (float*)(ws + OFF_R1);
    float* para = (float*)(ws + OFF_PARA);

    hipLaunchKernelGGL(k_zero, dim3((XT_BYTES / 16 + 255) / 256), dim3(256), 0, stream, xt);
    hipLaunchKernelGGL(k_transpose, dim3(B_ * H_), dim3(128), 0, stream, x, xt);
    hipLaunchKernelGGL(k_prepA, dim3(64), dim3(256), 0, stream, W, Am);
    hipLaunchKernelGGL(k_pred1, dim3(B_ * P_ / 256), dim3(256), 0, stream, x, pw, pb, r1);
    hipLaunchKernelGGL(k_pred2, dim3(B_ * P_ / 256), dim3(256), 0, stream, r1, cw, cb, para);
    hipLaunchKernelGGL(k_main, dim3(512), dim3(512), 0, stream, xt, Am, para, out);
}

// Round 4
// 494.075 us; speedup vs baseline: 1.1632x; 1.1632x over previous
//
#include <hip/hip_runtime.h>

typedef __attribute__((ext_vector_type(8))) short short8;
typedef __attribute__((ext_vector_type(8))) __bf16 bf16x8;
typedef __attribute__((ext_vector_type(4))) float f32x4;

// sizes
#define B_ 4
#define C_ 64
#define H_ 128
#define W_ 128
#define P_ (H_*W_)      // 16384
#define E_ 16
#define Kk 3

// ws layout (bytes)
#define OFF_XT   0u
#define XT_BYTES (4u*130u*130u*64u*2u)          // 8,652,800
#define OFF_A    8652800u
#define A_BYTES  (1024u*576u*2u)                 // 1,179,648
#define OFF_R1   9832448u
#define R1_BYTES (4u*16u*16384u*4u)              // 4,194,304
#define OFF_PARA 14026752u

__device__ inline unsigned short f2bf(float f) {
    union { float f; unsigned u; } v; v.f = f;
    unsigned r = v.u + 0x7FFF + ((v.u >> 16) & 1);
    return (unsigned short)(r >> 16);
}

// ---------- zero xt (borders must be 0; simpler to zero all) ----------
__global__ __launch_bounds__(256) void k_zero(unsigned short* __restrict__ xt) {
    int i = blockIdx.x * 256 + threadIdx.x;
    if (i < (int)(XT_BYTES / 16)) {
        short8 z = {0,0,0,0,0,0,0,0};
        ((short8*)xt)[i] = z;
    }
}

// ---------- transpose+pad x (NCHW f32) -> xt[b][y+1][x+1][c] bf16 ----------
__global__ __launch_bounds__(128) void k_transpose(const float* __restrict__ x,
                                                   unsigned short* __restrict__ xt) {
    int b = blockIdx.x >> 7, y = blockIdx.x & 127;
    int t = threadIdx.x; // x coordinate
    const float* src = x + (size_t)b * C_ * P_ + y * W_ + t;
    unsigned short* dst = xt + ((size_t)(b * 130 + y + 1) * 130 + t + 1) * 64;
#pragma unroll
    for (int i = 0; i < 8; ++i) {
        short8 v;
#pragma unroll
        for (int j = 0; j < 8; ++j) v[j] = (short)f2bf(src[(size_t)(i * 8 + j) * P_]);
        ((short8*)dst)[i] = v;
    }
}

// ---------- build A3 (fragment-linear) from W ----------
// A3[g][ks][f][lane][j], g = o>>2 (chunk-group), f = o&3, lane=(lhi*16+llo), j in [0,8)
// element = Wrow[(o*16 + llo)][col = ks*32 + lhi*8 + j], col = tap*64 + c
// Wsrc per o: [j' = c*9 + tap][e] -> Wsrc[o*9216 + (c*9+tap)*16 + e]
__global__ __launch_bounds__(256) void k_prepA(const float* __restrict__ Wsrc,
                                               unsigned short* __restrict__ A) {
    __shared__ float lw[9216];
    int o = blockIdx.x, t = threadIdx.x;
    const float* src = Wsrc + (size_t)o * 9216;
    for (int lin = t; lin < 9216; lin += 256) lw[lin] = src[lin];
    __syncthreads();
    int g = o >> 2, f = o & 3;
    unsigned short* dst = A + ((size_t)g * 72 + f) * 512; // + ks*4*512 + rem
    for (int lin = t; lin < 9216; lin += 256) {
        int ks = lin >> 9, rem = lin & 511;
        int lane = rem >> 3, j = rem & 7;
        int llo = lane & 15, lhi = lane >> 4;
        int col = ks * 32 + lhi * 8 + j;
        int tap = col >> 6, c = col & 63;
        dst[(size_t)ks * 2048 + rem] = f2bf(lw[(c * 9 + tap) * 16 + llo]);
    }
}

// ---------- predictor conv1x1 + relu -> r1[b][e][p] f32 ----------
__global__ __launch_bounds__(256) void k_pred1(const float* __restrict__ x,
                                               const float* __restrict__ pw,
                                               const float* __restrict__ pb,
                                               float* __restrict__ r1) {
    __shared__ float lpw[1024];
    __shared__ float lpb[16];
    int t = threadIdx.x;
    for (int lin = t; lin < 1024; lin += 256) lpw[lin] = pw[lin];
    if (t < 16) lpb[t] = pb[t];
    __syncthreads();
    int gp = blockIdx.x * 256 + t;
    int b = gp >> 14, p = gp & 16383;
    const float* xs = x + (size_t)b * C_ * P_ + p;
    float s[16];
#pragma unroll
    for (int e = 0; e < 16; ++e) s[e] = lpb[e];
    for (int c = 0; c < 64; ++c) {
        float xv = xs[(size_t)c * P_];
#pragma unroll
        for (int e = 0; e < 16; ++e) s[e] = fmaf(lpw[e * 64 + c], xv, s[e]);
    }
    float* d = r1 + (size_t)b * 16 * P_ + p;
#pragma unroll
    for (int e = 0; e < 16; ++e) d[(size_t)e * P_] = fmaxf(s[e], 0.f);
}

// ---------- predictor conv3x3 -> para[b][e][p] f32 ----------
__global__ __launch_bounds__(256) void k_pred2(const float* __restrict__ r1,
                                               const float* __restrict__ cw,
                                               const float* __restrict__ cb,
                                               float* __restrict__ para) {
    __shared__ float lcw[2304];
    __shared__ float lcb[16];
    int t = threadIdx.x;
    for (int lin = t; lin < 2304; lin += 256) lcw[lin] = cw[lin];
    if (t < 16) lcb[t] = cb[t];
    __syncthreads();
    int gp = blockIdx.x * 256 + t;
    int b = gp >> 14, p = gp & 16383;
    int y = p >> 7, xc = p & 127;
    const float* rs = r1 + (size_t)b * 16 * P_;
    float s[16];
#pragma unroll
    for (int e = 0; e < 16; ++e) s[e] = lcb[e];
    for (int dy = 0; dy < 3; ++dy) {
        int yy = y + dy - 1;
        if (yy < 0 || yy > 127) continue;
        for (int dx = 0; dx < 3; ++dx) {
            int xv = xc + dx - 1;
            if (xv < 0 || xv > 127) continue;
            int q = yy * 128 + xv;
            int tap = dy * 3 + dx;
#pragma unroll
            for (int ep = 0; ep < 16; ++ep) {
                float v = rs[(size_t)ep * P_ + q];
#pragma unroll
                for (int e = 0; e < 16; ++e)
                    s[e] = fmaf(lcw[(e * 16 + ep) * 9 + tap], v, s[e]);
            }
        }
    }
    float* d = para + (size_t)b * 16 * P_ + p;
#pragma unroll
    for (int e = 0; e < 16; ++e) d[(size_t)e * P_] = s[e];
}

// ---------- main fused kernel ----------
// block = 512 threads (8 waves): 4 image rows x 16 output channels (osl).
// wave: wrow = wave&3 (image row), ohalf = wave>>2 (8 o's via 2 chunks x 4 f).
// ks-loop fully unrolled with static addressing; compiler schedules the
// pipeline (pressure-aware, unlike R3's manual dbuf which spilled).
__global__ __launch_bounds__(512, 2) void k_main(const unsigned short* __restrict__ xt,
                                                 const unsigned short* __restrict__ A,
                                                 const float* __restrict__ para,
                                                 float* __restrict__ out) {
    __shared__ unsigned short lds[6 * 130 * 64]; // 99,840 B
    int r = blockIdx.x;
    int xcd = r & 7;
    int ord = r >> 3;
    int osl = ord & 3;          // o-slice: 16 o's
    int bygl = ord >> 2;        // [0,16)
    int byg = bygl * 8 + xcd;   // [0,128)
    int b = byg >> 5, yg = byg & 31;
    int y0 = yg * 4;            // first image row of this block

    int tid = threadIdx.x;
    int wave = tid >> 6, lane = tid & 63, lhi = lane >> 4, llo = lane & 15;
    int wrow = wave & 3, ohalf = wave >> 2;

    // stage 6 padded xt rows (y0 .. y0+5), swizzle byte ^= ((xx&7)<<4)
    const unsigned short* xrow = xt + (size_t)(b * 130 + y0) * 130 * 64;
    for (int ci = tid; ci < 6240; ci += 512) {
        int row = ci / 1040, rem = ci - row * 1040;
        int xx = rem >> 3, cc = rem & 7;
        short8 v = *(const short8*)(xrow + ((size_t)row * 130 + xx) * 64 + cc * 8);
        int lb = row * 16640 + xx * 128 + ((cc * 16) ^ ((xx & 7) << 4));
        *(short8*)((char*)lds + lb) = v;
    }
    __syncthreads();

    int y = y0 + wrow;
    const float* pp = para + (size_t)b * 16 * P_ + y * 128;
    float* po = out + (size_t)b * 64 * P_ + y * 128;

    // precomputed LDS read vaddrs: qv[parity][kw]; full addr = qv + kh*16640 + pg*2048
    int qv[2][3];
#pragma unroll
    for (int kw = 0; kw < 3; ++kw) {
        int rowi = llo + kw;
        int base0 = wrow * 16640 + rowi * 128 + ((lhi * 16) ^ ((rowi & 7) << 4));
        qv[0][kw] = base0;
        qv[1][kw] = base0 ^ 64;
    }
    const char* ldsc = (const char*)lds;

#pragma unroll 1
    for (int chunk = 0; chunk < 2; ++chunk) {
        int obase = osl * 16 + ohalf * 8 + chunk * 4;
        int g = obase >> 2; // chunk-group index into A3
        const unsigned short* Ag = A + (size_t)g * 72 * 512 + lane * 8;

        f32x4 acc[4][8];
#pragma unroll
        for (int f = 0; f < 4; ++f)
#pragma unroll
            for (int pg = 0; pg < 8; ++pg) acc[f][pg] = (f32x4){0.f, 0.f, 0.f, 0.f};

#pragma unroll
        for (int ks = 0; ks < 18; ++ks) {
            const int kh = ks / 6;
            const int kw = (ks - kh * 6) >> 1;
            const int par = ks & 1;
            bf16x8 af[4];
#pragma unroll
            for (int f = 0; f < 4; ++f)
                af[f] = *(const bf16x8*)(Ag + (size_t)ks * 2048 + f * 512);
            const char* bp = ldsc + qv[par][kw] + kh * 16640;
            bf16x8 bf[8];
#pragma unroll
            for (int pg = 0; pg < 8; ++pg)
                bf[pg] = *(const bf16x8*)(bp + pg * 2048);
#pragma unroll
            for (int f = 0; f < 4; ++f)
#pragma unroll
                for (int pg = 0; pg < 8; ++pg)
                    acc[f][pg] = __builtin_amdgcn_mfma_f32_16x16x32_bf16(af[f], bf[pg], acc[f][pg], 0, 0, 0);
        }

        // epilogue: multiply rows (e) by para[e,p], reduce over e
        float pvv[8][4];
#pragma unroll
        for (int pg = 0; pg < 8; ++pg)
#pragma unroll
            for (int rr = 0; rr < 4; ++rr)
                pvv[pg][rr] = pp[(size_t)(lhi * 4 + rr) * P_ + pg * 16 + llo];

#pragma unroll
        for (int f = 0; f < 4; ++f) {
            int o = obase + f;
#pragma unroll
            for (int pg = 0; pg < 8; ++pg) {
                float s = acc[f][pg][0] * pvv[pg][0] + acc[f][pg][1] * pvv[pg][1] +
                          acc[f][pg][2] * pvv[pg][2] + acc[f][pg][3] * pvv[pg][3];
                s += __shfl_xor(s, 16);
                s += __shfl_xor(s, 32);
                if (lhi == 0)
                    __builtin_nontemporal_store(s, &po[(size_t)o * P_ + pg * 16 + llo]);
            }
        }
    }
}

extern "C" void kernel_launch(void* const* d_in, const int* in_sizes, int n_in,
                              void* d_out, int out_size, void* d_ws, size_t ws_size,
                              hipStream_t stream) {
    const float* x  = (const float*)d_in[0];
    const float* W  = (const float*)d_in[1];
    const float* pw = (const float*)d_in[2];
    const float* pb = (const float*)d_in[3];
    const float* cw = (const float*)d_in[4];
    const float* cb = (const float*)d_in[5];
    float* out = (float*)d_out;
    char* ws = (char*)d_ws;
    unsigned short* xt = (unsigned short*)(ws + OFF_XT);
    unsigned short* Am = (unsigned short*)(ws + OFF_A);
    float* r1   = (float*)(ws + OFF_R1);
    float* para = (float*)(ws + OFF_PARA);

    hipLaunchKernelGGL(k_zero, dim3((XT_BYTES / 16 + 255) / 256), dim3(256), 0, stream, xt);
    hipLaunchKernelGGL(k_transpose, dim3(B_ * H_), dim3(128), 0, stream, x, xt);
    hipLaunchKernelGGL(k_prepA, dim3(64), dim3(256), 0, stream, W, Am);
    hipLaunchKernelGGL(k_pred1, dim3(B_ * P_ / 256), dim3(256), 0, stream, x, pw, pb, r1);
    hipLaunchKernelGGL(k_pred2, dim3(B_ * P_ / 256), dim3(256), 0, stream, r1, cw, cb, para);
    hipLaunchKernelGGL(k_main, dim3(512), dim3(512), 0, stream, xt, Am, para, out);
}

// Round 5
// 405.373 us; speedup vs baseline: 1.4178x; 1.2188x over previous
//
#include <hip/hip_runtime.h>

typedef __attribute__((ext_vector_type(8))) short short8;
typedef __attribute__((ext_vector_type(8))) __bf16 bf16x8;
typedef __attribute__((ext_vector_type(4))) float f32x4;

// sizes
#define B_ 4
#define C_ 64
#define H_ 128
#define W_ 128
#define P_ (H_*W_)      // 16384
#define E_ 16
#define Kk 3

// ws layout (bytes)
#define OFF_XT   0u
#define XT_BYTES (4u*130u*130u*64u*2u)          // 8,652,800
#define OFF_A    8652800u
#define A_BYTES  (1024u*576u*2u)                 // 1,179,648
#define OFF_R1   9832448u
#define R1_BYTES (4u*16u*16384u*4u)              // 4,194,304
#define OFF_PARA 14026752u

__device__ inline unsigned short f2bf(float f) {
    union { float f; unsigned u; } v; v.f = f;
    unsigned r = v.u + 0x7FFF + ((v.u >> 16) & 1);
    return (unsigned short)(r >> 16);
}

// ---------- zero xt (borders must be 0; simpler to zero all) ----------
__global__ __launch_bounds__(256) void k_zero(unsigned short* __restrict__ xt) {
    int i = blockIdx.x * 256 + threadIdx.x;
    if (i < (int)(XT_BYTES / 16)) {
        short8 z = {0,0,0,0,0,0,0,0};
        ((short8*)xt)[i] = z;
    }
}

// ---------- transpose+pad x (NCHW f32) -> xt[b][y+1][x+1][c] bf16 ----------
__global__ __launch_bounds__(128) void k_transpose(const float* __restrict__ x,
                                                   unsigned short* __restrict__ xt) {
    int b = blockIdx.x >> 7, y = blockIdx.x & 127;
    int t = threadIdx.x; // x coordinate
    const float* src = x + (size_t)b * C_ * P_ + y * W_ + t;
    unsigned short* dst = xt + ((size_t)(b * 130 + y + 1) * 130 + t + 1) * 64;
#pragma unroll
    for (int i = 0; i < 8; ++i) {
        short8 v;
#pragma unroll
        for (int j = 0; j < 8; ++j) v[j] = (short)f2bf(src[(size_t)(i * 8 + j) * P_]);
        ((short8*)dst)[i] = v;
    }
}

// ---------- build A[row=o*16+e][col=(kh*3+kw)*64+c] bf16 from W ----------
__global__ __launch_bounds__(256) void k_prepA(const float* __restrict__ Wsrc,
                                               unsigned short* __restrict__ A) {
    __shared__ float lw[9216];
    int o = blockIdx.x, t = threadIdx.x;
    const float* src = Wsrc + (size_t)o * 9216; // 576*16 per o, layout [j=c*9+tap][e]
    for (int lin = t; lin < 9216; lin += 256) lw[lin] = src[lin];
    __syncthreads();
    unsigned short* dst = A + (size_t)o * 16 * 576;
    for (int lin = t; lin < 9216; lin += 256) {
        int e = lin / 576, col = lin - e * 576;
        int tap = col >> 6, c = col & 63;
        dst[e * 576 + col] = f2bf(lw[(c * 9 + tap) * 16 + e]);
    }
}

// ---------- predictor conv1x1 + relu -> r1[b][e][p] f32 ----------
__global__ __launch_bounds__(256) void k_pred1(const float* __restrict__ x,
                                               const float* __restrict__ pw,
                                               const float* __restrict__ pb,
                                               float* __restrict__ r1) {
    __shared__ float lpw[1024];
    __shared__ float lpb[16];
    int t = threadIdx.x;
    for (int lin = t; lin < 1024; lin += 256) lpw[lin] = pw[lin];
    if (t < 16) lpb[t] = pb[t];
    __syncthreads();
    int gp = blockIdx.x * 256 + t;
    int b = gp >> 14, p = gp & 16383;
    const float* xs = x + (size_t)b * C_ * P_ + p;
    float s[16];
#pragma unroll
    for (int e = 0; e < 16; ++e) s[e] = lpb[e];
    for (int c = 0; c < 64; ++c) {
        float xv = xs[(size_t)c * P_];
#pragma unroll
        for (int e = 0; e < 16; ++e) s[e] = fmaf(lpw[e * 64 + c], xv, s[e]);
    }
    float* d = r1 + (size_t)b * 16 * P_ + p;
#pragma unroll
    for (int e = 0; e < 16; ++e) d[(size_t)e * P_] = fmaxf(s[e], 0.f);
}

// ---------- predictor conv3x3 -> para[b][e][p] f32 ----------
__global__ __launch_bounds__(256) void k_pred2(const float* __restrict__ r1,
                                               const float* __restrict__ cw,
                                               const float* __restrict__ cb,
                                               float* __restrict__ para) {
    __shared__ float lcw[2304];
    __shared__ float lcb[16];
    int t = threadIdx.x;
    for (int lin = t; lin < 2304; lin += 256) lcw[lin] = cw[lin];
    if (t < 16) lcb[t] = cb[t];
    __syncthreads();
    int gp = blockIdx.x * 256 + t;
    int b = gp >> 14, p = gp & 16383;
    int y = p >> 7, xc = p & 127;
    const float* rs = r1 + (size_t)b * 16 * P_;
    float s[16];
#pragma unroll
    for (int e = 0; e < 16; ++e) s[e] = lcb[e];
    for (int dy = 0; dy < 3; ++dy) {
        int yy = y + dy - 1;
        if (yy < 0 || yy > 127) continue;
        for (int dx = 0; dx < 3; ++dx) {
            int xv = xc + dx - 1;
            if (xv < 0 || xv > 127) continue;
            int q = yy * 128 + xv;
            int tap = dy * 3 + dx;
#pragma unroll
            for (int ep = 0; ep < 16; ++ep) {
                float v = rs[(size_t)ep * P_ + q];
#pragma unroll
                for (int e = 0; e < 16; ++e)
                    s[e] = fmaf(lcw[(e * 16 + ep) * 9 + tap], v, s[e]);
            }
        }
    }
    float* d = para + (size_t)b * 16 * P_ + p;
#pragma unroll
    for (int e = 0; e < 16; ++e) d[(size_t)e * P_] = s[e];
}

// ---------- main fused kernel ----------
// 256-thread block (4 waves), 1 image row, 16 o's (osl). 3 staged xt rows =
// 49,920 B LDS -> 3 blocks/CU = 3 waves/SIMD (the R2->R5 occupancy lever).
// wave = (ohalf, phalf): 4 o's x 64 px per chunk, 2 chunks; acc[4][4]=64 regs.
// Waves {0,2} and {1,3} read identical A streams -> L1 reuse.
// Loop body is byte-identical in style to the proven R2 kernel.
__global__ __launch_bounds__(256, 3) void k_main(const unsigned short* __restrict__ xt,
                                                 const unsigned short* __restrict__ A,
                                                 const float* __restrict__ para,
                                                 float* __restrict__ out) {
    __shared__ unsigned short lds[3 * 130 * 64]; // 49,920 B
    int r = blockIdx.x;
    int xcd = r & 7;
    int ord = r >> 3;           // [0,256)
    int osl = ord & 3;          // o-slice: 16 o's
    int yl = ord >> 2;          // [0,64)
    int rowid = xcd * 64 + yl;  // contiguous 64-row slab per XCD
    int b = rowid >> 7, y = rowid & 127;

    int tid = threadIdx.x;
    int wave = tid >> 6, lane = tid & 63, lhi = lane >> 4, llo = lane & 15;
    int ohalf = wave & 1, phalf = wave >> 1;

    // stage 3 padded xt rows (y .. y+2), swizzle byte ^= ((xx&7)<<4)
    const unsigned short* xrow = xt + (size_t)(b * 130 + y) * 130 * 64;
    for (int ci = tid; ci < 3120; ci += 256) {
        int row = ci / 1040, rem = ci - row * 1040;
        int xx = rem >> 3, cc = rem & 7;
        short8 v = *(const short8*)(xrow + ((size_t)row * 130 + xx) * 64 + cc * 8);
        int lb = row * 16640 + xx * 128 + ((cc * 16) ^ ((xx & 7) << 4));
        *(short8*)((char*)lds + lb) = v;
    }
    __syncthreads();

    const float* pp = para + (size_t)b * 16 * P_ + y * 128 + phalf * 64;
    float* po = out + (size_t)b * 64 * P_ + y * 128 + phalf * 64;

    // precomputed LDS read vaddrs: qv[parity][kw]; full addr = qv + kh*16640 + pg*2048
    int qv[2][3];
#pragma unroll
    for (int kw = 0; kw < 3; ++kw) {
        int rowi = phalf * 64 + llo + kw;
        int base0 = rowi * 128 + ((lhi * 16) ^ ((rowi & 7) << 4));
        qv[0][kw] = base0;
        qv[1][kw] = base0 ^ 64;
    }
    const char* ldsc = (const char*)lds;

    for (int chunk = 0; chunk < 2; ++chunk) {
        int obase = osl * 16 + ohalf * 8 + chunk * 4;
        const unsigned short* Ab = A + (size_t)(obase * 16 + llo) * 576 + lhi * 8;

        f32x4 acc[4][4];
#pragma unroll
        for (int f = 0; f < 4; ++f)
#pragma unroll
            for (int pg = 0; pg < 4; ++pg) acc[f][pg] = (f32x4){0.f, 0.f, 0.f, 0.f};

        for (int ks = 0; ks < 18; ++ks) {
            int kh = ks / 6, r6 = ks - kh * 6;
            int kw = r6 >> 1;
            bf16x8 af[4];
#pragma unroll
            for (int f = 0; f < 4; ++f)
                af[f] = *(const bf16x8*)(Ab + (size_t)f * 9216 + ks * 32);
            const char* bp = ldsc + qv[ks & 1][kw] + kh * 16640;
            bf16x8 bf[4];
#pragma unroll
            for (int pg = 0; pg < 4; ++pg)
                bf[pg] = *(const bf16x8*)(bp + pg * 2048);
#pragma unroll
            for (int f = 0; f < 4; ++f)
#pragma unroll
                for (int pg = 0; pg < 4; ++pg)
                    acc[f][pg] = __builtin_amdgcn_mfma_f32_16x16x32_bf16(af[f], bf[pg], acc[f][pg], 0, 0, 0);
        }

        // epilogue: multiply rows (e) by para[e,p], reduce over e
        float pvv[4][4];
#pragma unroll
        for (int pg = 0; pg < 4; ++pg)
#pragma unroll
            for (int rr = 0; rr < 4; ++rr)
                pvv[pg][rr] = pp[(size_t)(lhi * 4 + rr) * P_ + pg * 16 + llo];

#pragma unroll
        for (int f = 0; f < 4; ++f) {
            int o = obase + f;
#pragma unroll
            for (int pg = 0; pg < 4; ++pg) {
                float s = acc[f][pg][0] * pvv[pg][0] + acc[f][pg][1] * pvv[pg][1] +
                          acc[f][pg][2] * pvv[pg][2] + acc[f][pg][3] * pvv[pg][3];
                s += __shfl_xor(s, 16);
                s += __shfl_xor(s, 32);
                if (lhi == 0)
                    __builtin_nontemporal_store(s, &po[(size_t)o * P_ + pg * 16 + llo]);
            }
        }
    }
}

extern "C" void kernel_launch(void* const* d_in, const int* in_sizes, int n_in,
                              void* d_out, int out_size, void* d_ws, size_t ws_size,
                              hipStream_t stream) {
    const float* x  = (const float*)d_in[0];
    const float* W  = (const float*)d_in[1];
    const float* pw = (const float*)d_in[2];
    const float* pb = (const float*)d_in[3];
    const float* cw = (const float*)d_in[4];
    const float* cb = (const float*)d_in[5];
    float* out = (float*)d_out;
    char* ws = (char*)d_ws;
    unsigned short* xt = (unsigned short*)(ws + OFF_XT);
    unsigned short* Am = (unsigned short*)(ws + OFF_A);
    float* r1   = (float*)(ws + OFF_R1);
    float* para = (float*)(ws + OFF_PARA);

    hipLaunchKernelGGL(k_zero, dim3((XT_BYTES / 16 + 255) / 256), dim3(256), 0, stream, xt);
    hipLaunchKernelGGL(k_transpose, dim3(B_ * H_), dim3(128), 0, stream, x, xt);
    hipLaunchKernelGGL(k_prepA, dim3(64), dim3(256), 0, stream, W, Am);
    hipLaunchKernelGGL(k_pred1, dim3(B_ * P_ / 256), dim3(256), 0, stream, x, pw, pb, r1);
    hipLaunchKernelGGL(k_pred2, dim3(B_ * P_ / 256), dim3(256), 0, stream, r1, cw, cb, para);
    hipLaunchKernelGGL(k_main, dim3(2048), dim3(256), 0, stream, xt, Am, para, out);
}

// Round 6
// 139.985 us; speedup vs baseline: 4.1056x; 2.8958x over previous
//
#include <hip/hip_runtime.h>

typedef __attribute__((ext_vector_type(8))) short short8;
typedef __attribute__((ext_vector_type(8))) __bf16 bf16x8;
typedef __attribute__((ext_vector_type(4))) float f32x4;

// sizes
#define B_ 4
#define C_ 64
#define H_ 128
#define W_ 128
#define P_ (H_*W_)      // 16384
#define E_ 16
#define Kk 3

// ws layout (bytes)
#define OFF_XT   0u
#define XT_BYTES (4u*130u*130u*64u*2u)          // 8,652,800
#define OFF_A    8652800u
#define A_BYTES  (1024u*576u*2u)                 // 1,179,648
#define OFF_R1   9832448u
#define R1_BYTES (4u*16u*16384u*4u)              // 4,194,304
#define OFF_PARA 14026752u

__device__ inline unsigned short f2bf(float f) {
    union { float f; unsigned u; } v; v.f = f;
    unsigned r = v.u + 0x7FFF + ((v.u >> 16) & 1);
    return (unsigned short)(r >> 16);
}

// ---------- zero xt (borders must be 0; simpler to zero all) ----------
__global__ __launch_bounds__(256) void k_zero(unsigned short* __restrict__ xt) {
    int i = blockIdx.x * 256 + threadIdx.x;
    if (i < (int)(XT_BYTES / 16)) {
        short8 z = {0,0,0,0,0,0,0,0};
        ((short8*)xt)[i] = z;
    }
}

// ---------- transpose+pad x (NCHW f32) -> xt[b][y+1][x+1][c] bf16 ----------
__global__ __launch_bounds__(128) void k_transpose(const float* __restrict__ x,
                                                   unsigned short* __restrict__ xt) {
    int b = blockIdx.x >> 7, y = blockIdx.x & 127;
    int t = threadIdx.x; // x coordinate
    const float* src = x + (size_t)b * C_ * P_ + y * W_ + t;
    unsigned short* dst = xt + ((size_t)(b * 130 + y + 1) * 130 + t + 1) * 64;
#pragma unroll
    for (int i = 0; i < 8; ++i) {
        short8 v;
#pragma unroll
        for (int j = 0; j < 8; ++j) v[j] = (short)f2bf(src[(size_t)(i * 8 + j) * P_]);
        ((short8*)dst)[i] = v;
    }
}

// ---------- build A[row=o*16+e][col=(kh*3+kw)*64+c] bf16 from W ----------
__global__ __launch_bounds__(256) void k_prepA(const float* __restrict__ Wsrc,
                                               unsigned short* __restrict__ A) {
    __shared__ float lw[9216];
    int o = blockIdx.x, t = threadIdx.x;
    const float* src = Wsrc + (size_t)o * 9216; // 576*16 per o, layout [j=c*9+tap][e]
    for (int lin = t; lin < 9216; lin += 256) lw[lin] = src[lin];
    __syncthreads();
    unsigned short* dst = A + (size_t)o * 16 * 576;
    for (int lin = t; lin < 9216; lin += 256) {
        int e = lin / 576, col = lin - e * 576;
        int tap = col >> 6, c = col & 63;
        dst[e * 576 + col] = f2bf(lw[(c * 9 + tap) * 16 + e]);
    }
}

// ---------- predictor conv1x1 + relu -> r1[b][e][p] f32 ----------
__global__ __launch_bounds__(256) void k_pred1(const float* __restrict__ x,
                                               const float* __restrict__ pw,
                                               const float* __restrict__ pb,
                                               float* __restrict__ r1) {
    __shared__ float lpw[1024];
    __shared__ float lpb[16];
    int t = threadIdx.x;
    for (int lin = t; lin < 1024; lin += 256) lpw[lin] = pw[lin];
    if (t < 16) lpb[t] = pb[t];
    __syncthreads();
    int gp = blockIdx.x * 256 + t;
    int b = gp >> 14, p = gp & 16383;
    const float* xs = x + (size_t)b * C_ * P_ + p;
    float s[16];
#pragma unroll
    for (int e = 0; e < 16; ++e) s[e] = lpb[e];
    for (int c = 0; c < 64; ++c) {
        float xv = xs[(size_t)c * P_];
#pragma unroll
        for (int e = 0; e < 16; ++e) s[e] = fmaf(lpw[e * 64 + c], xv, s[e]);
    }
    float* d = r1 + (size_t)b * 16 * P_ + p;
#pragma unroll
    for (int e = 0; e < 16; ++e) d[(size_t)e * P_] = fmaxf(s[e], 0.f);
}

// ---------- predictor conv3x3 -> para[b][e][p] f32 ----------
__global__ __launch_bounds__(256) void k_pred2(const float* __restrict__ r1,
                                               const float* __restrict__ cw,
                                               const float* __restrict__ cb,
                                               float* __restrict__ para) {
    __shared__ float lcw[2304];
    __shared__ float lcb[16];
    int t = threadIdx.x;
    for (int lin = t; lin < 2304; lin += 256) lcw[lin] = cw[lin];
    if (t < 16) lcb[t] = cb[t];
    __syncthreads();
    int gp = blockIdx.x * 256 + t;
    int b = gp >> 14, p = gp & 16383;
    int y = p >> 7, xc = p & 127;
    const float* rs = r1 + (size_t)b * 16 * P_;
    float s[16];
#pragma unroll
    for (int e = 0; e < 16; ++e) s[e] = lcb[e];
    for (int dy = 0; dy < 3; ++dy) {
        int yy = y + dy - 1;
        if (yy < 0 || yy > 127) continue;
        for (int dx = 0; dx < 3; ++dx) {
            int xv = xc + dx - 1;
            if (xv < 0 || xv > 127) continue;
            int q = yy * 128 + xv;
            int tap = dy * 3 + dx;
#pragma unroll
            for (int ep = 0; ep < 16; ++ep) {
                float v = rs[(size_t)ep * P_ + q];
#pragma unroll
                for (int e = 0; e < 16; ++e)
                    s[e] = fmaf(lcw[(e * 16 + ep) * 9 + tap], v, s[e]);
            }
        }
    }
    float* d = para + (size_t)b * 16 * P_ + p;
#pragma unroll
    for (int e = 0; e < 16; ++e) d[(size_t)e * P_] = s[e];
}

// ---------- main fused kernel ----------
// R2-proven skeleton: 512 threads (8 waves), 4 image rows x 16 o's, LDS 99,840B
// (1 block/CU, 2 waves/SIMD), acc[4][8] per chunk. New in R6:
//  - ks-loop as kh*kw*parity nested runtime loops (unroll-pinned), two static
//    half-bodies with A-fragment 1-deep prefetch (afA/afB) so L2 latency hides
//    under the 32-MFMA burst.
//  - pvv (para) loads moved to the epilogue (frees 32 regs during hot loop).
//  - s_setprio(1) around MFMA bursts.
__global__ __launch_bounds__(512, 2) void k_main(const unsigned short* __restrict__ xt,
                                                 const unsigned short* __restrict__ A,
                                                 const float* __restrict__ para,
                                                 float* __restrict__ out) {
    __shared__ unsigned short lds[6 * 130 * 64]; // 99,840 B
    int r = blockIdx.x;
    int xcd = r & 7;
    int ord = r >> 3;
    int osl = ord & 3;          // o-slice: 16 o's
    int bygl = ord >> 2;        // [0,16)
    int byg = bygl * 8 + xcd;   // [0,128)
    int b = byg >> 5, yg = byg & 31;
    int y0 = yg * 4;            // first image row of this block

    int tid = threadIdx.x;
    int wave = tid >> 6, lane = tid & 63, lhi = lane >> 4, llo = lane & 15;
    int wrow = wave & 3, ohalf = wave >> 2;

    // stage 6 padded xt rows (y0 .. y0+5), swizzle byte ^= ((xx&7)<<4)
    const unsigned short* xrow = xt + (size_t)(b * 130 + y0) * 130 * 64;
    for (int ci = tid; ci < 6240; ci += 512) {
        int row = ci / 1040, rem = ci - row * 1040;
        int xx = rem >> 3, cc = rem & 7;
        short8 v = *(const short8*)(xrow + ((size_t)row * 130 + xx) * 64 + cc * 8);
        int lb = row * 16640 + xx * 128 + ((cc * 16) ^ ((xx & 7) << 4));
        *(short8*)((char*)lds + lb) = v;
    }
    __syncthreads();

    int y = y0 + wrow;
    const float* pp = para + (size_t)b * 16 * P_ + y * 128;
    float* po = out + (size_t)b * 64 * P_ + y * 128;

    // precomputed LDS read vaddrs: qv[parity][kw]; full addr = qv + kh*16640 + pg*2048
    int qv[2][3];
#pragma unroll
    for (int kw = 0; kw < 3; ++kw) {
        int rowi = llo + kw;
        int base0 = wrow * 16640 + rowi * 128 + ((lhi * 16) ^ ((rowi & 7) << 4));
        qv[0][kw] = base0;
        qv[1][kw] = base0 ^ 64;
    }
    const char* ldsc = (const char*)lds;

#pragma unroll 1
    for (int chunk = 0; chunk < 2; ++chunk) {
        int obase = osl * 16 + ohalf * 8 + chunk * 4;
        const unsigned short* Ab = A + (size_t)(obase * 16 + llo) * 576 + lhi * 8;

        f32x4 acc[4][8];
#pragma unroll
        for (int f = 0; f < 4; ++f)
#pragma unroll
            for (int pg = 0; pg < 8; ++pg) acc[f][pg] = (f32x4){0.f, 0.f, 0.f, 0.f};

        bf16x8 afA[4], afB[4];
        // prologue: A-frags for ks=0
#pragma unroll
        for (int f = 0; f < 4; ++f)
            afA[f] = *(const bf16x8*)(Ab + (size_t)f * 9216);

#pragma unroll 1
        for (int kh = 0; kh < 3; ++kh) {
#pragma unroll 1
            for (int kw = 0; kw < 3; ++kw) {
                const int ksc = kh * 6 + kw * 2; // current even ks
                const char* bprow = ldsc + kh * 16640;
                // ---- half 0 (parity 0): compute with afA, prefetch ksc+1 -> afB
                {
#pragma unroll
                    for (int f = 0; f < 4; ++f)
                        afB[f] = *(const bf16x8*)(Ab + (size_t)f * 9216 + (ksc + 1) * 32);
                    const char* bp = bprow + qv[0][kw];
                    bf16x8 bf[8];
#pragma unroll
                    for (int pg = 0; pg < 8; ++pg)
                        bf[pg] = *(const bf16x8*)(bp + pg * 2048);
                    __builtin_amdgcn_s_setprio(1);
#pragma unroll
                    for (int f = 0; f < 4; ++f)
#pragma unroll
                        for (int pg = 0; pg < 8; ++pg)
                            acc[f][pg] = __builtin_amdgcn_mfma_f32_16x16x32_bf16(afA[f], bf[pg], acc[f][pg], 0, 0, 0);
                    __builtin_amdgcn_s_setprio(0);
                }
                // ---- half 1 (parity 1): compute with afB, prefetch ksc+2 -> afA
                {
                    // ksc+2==18 at the very end reads 48B past this chunk's A
                    // slice (still inside ws) -- harmless, overwritten next chunk.
#pragma unroll
                    for (int f = 0; f < 4; ++f)
                        afA[f] = *(const bf16x8*)(Ab + (size_t)f * 9216 + (ksc + 2) * 32);
                    const char* bp = bprow + qv[1][kw];
                    bf16x8 bf[8];
#pragma unroll
                    for (int pg = 0; pg < 8; ++pg)
                        bf[pg] = *(const bf16x8*)(bp + pg * 2048);
                    __builtin_amdgcn_s_setprio(1);
#pragma unroll
                    for (int f = 0; f < 4; ++f)
#pragma unroll
                        for (int pg = 0; pg < 8; ++pg)
                            acc[f][pg] = __builtin_amdgcn_mfma_f32_16x16x32_bf16(afB[f], bf[pg], acc[f][pg], 0, 0, 0);
                    __builtin_amdgcn_s_setprio(0);
                }
            }
        }

        // epilogue: multiply rows (e) by para[e,p], reduce over e
        float pvv[8][4];
#pragma unroll
        for (int pg = 0; pg < 8; ++pg)
#pragma unroll
            for (int rr = 0; rr < 4; ++rr)
                pvv[pg][rr] = pp[(size_t)(lhi * 4 + rr) * P_ + pg * 16 + llo];

#pragma unroll
        for (int f = 0; f < 4; ++f) {
            int o = obase + f;
#pragma unroll
            for (int pg = 0; pg < 8; ++pg) {
                float s = acc[f][pg][0] * pvv[pg][0] + acc[f][pg][1] * pvv[pg][1] +
                          acc[f][pg][2] * pvv[pg][2] + acc[f][pg][3] * pvv[pg][3];
                s += __shfl_xor(s, 16);
                s += __shfl_xor(s, 32);
                if (lhi == 0)
                    __builtin_nontemporal_store(s, &po[(size_t)o * P_ + pg * 16 + llo]);
            }
        }
    }
}

extern "C" void kernel_launch(void* const* d_in, const int* in_sizes, int n_in,
                              void* d_out, int out_size, void* d_ws, size_t ws_size,
                              hipStream_t stream) {
    const float* x  = (const float*)d_in[0];
    const float* W  = (const float*)d_in[1];
    const float* pw = (const float*)d_in[2];
    const float* pb = (const float*)d_in[3];
    const float* cw = (const float*)d_in[4];
    const float* cb = (const float*)d_in[5];
    float* out = (float*)d_out;
    char* ws = (char*)d_ws;
    unsigned short* xt = (unsigned short*)(ws + OFF_XT);
    unsigned short* Am = (unsigned short*)(ws + OFF_A);
    float* r1   = (float*)(ws + OFF_R1);
    float* para = (float*)(ws + OFF_PARA);

    hipLaunchKernelGGL(k_zero, dim3((XT_BYTES / 16 + 255) / 256), dim3(256), 0, stream, xt);
    hipLaunchKernelGGL(k_transpose, dim3(B_ * H_), dim3(128), 0, stream, x, xt);
    hipLaunchKernelGGL(k_prepA, dim3(64), dim3(256), 0, stream, W, Am);
    hipLaunchKernelGGL(k_pred1, dim3(B_ * P_ / 256), dim3(256), 0, stream, x, pw, pb, r1);
    hipLaunchKernelGGL(k_pred2, dim3(B_ * P_ / 256), dim3(256), 0, stream, r1, cw, cb, para);
    hipLaunchKernelGGL(k_main, dim3(512), dim3(512), 0, stream, xt, Am, para, out);
}